// Round 1
// baseline (1539.842 us; speedup 1.0000x reference)
//
#include <hip/hip_runtime.h>
#include <hip/hip_bf16.h>
#include <climits>

#define N_NODES   100000
#define N_EDGES   1600000
#define D         64
#define N_GRAPHS  32
#define N_CLASSES 40

// Monotone bijection float -> int (order-preserving for signed int compare).
__device__ __forceinline__ int f2ord(float f) {
    int i = __float_as_int(f);
    return (i >= 0) ? i : (i ^ 0x7FFFFFFF);
}
__device__ __forceinline__ float ord2f(int i) {
    int j = (i >= 0) ? i : (i ^ 0x7FFFFFFF);
    return __int_as_float(j);
}

__global__ __launch_bounds__(256) void k_fill(int* __restrict__ p, long n, int v) {
    long i = (long)blockIdx.x * blockDim.x + threadIdx.x;
    long stride = (long)gridDim.x * blockDim.x;
    for (; i < n; i += stride) p[i] = v;
}

// t = h @ tw ; q = (h @ pw + (tb+pb)) - t.  One lane per output feature.
// FROM_AGG: input features come from the ordered-int agg buffer (sentinel INT_MIN -> 0).
template <bool FROM_AGG>
__global__ __launch_bounds__(256) void k_gemm_tq(
    const float* __restrict__ h, const int* __restrict__ agg,
    const float* __restrict__ tw, const float* __restrict__ pw,
    const float* __restrict__ tb, const float* __restrict__ pb,
    float* __restrict__ t, float* __restrict__ q)
{
    __shared__ float s_tw[D * D];
    __shared__ float s_pw[D * D];
    __shared__ float s_b[D];
    for (int i = threadIdx.x; i < D * D; i += 256) {
        s_tw[i] = tw[i];
        s_pw[i] = pw[i];
    }
    if (threadIdx.x < D) s_b[threadIdx.x] = tb[threadIdx.x] + pb[threadIdx.x];
    __syncthreads();

    const int lane = threadIdx.x & 63;
    const int wave = threadIdx.x >> 6;
    const int ROWS_PER_WAVE = 32;
    const int row0 = blockIdx.x * (ROWS_PER_WAVE * 4) + wave * ROWS_PER_WAVE;

    for (int r = 0; r < ROWS_PER_WAVE; ++r) {
        const int n = row0 + r;
        if (n >= N_NODES) return;  // rows per wave are contiguous; no later syncs
        float hreg;
        if (FROM_AGG) {
            int a = agg[(long)n * D + lane];
            hreg = (a == INT_MIN) ? 0.0f : ord2f(a);
        } else {
            hreg = h[(long)n * D + lane];
        }
        float acc_t = 0.0f;
        float acc_p = s_b[lane];
        #pragma unroll
        for (int k = 0; k < D; ++k) {
            float hk = __shfl(hreg, k);
            acc_t = fmaf(hk, s_tw[k * D + lane], acc_t);
            acc_p = fmaf(hk, s_pw[k * D + lane], acc_p);
        }
        t[(long)n * D + lane] = acc_t;
        q[(long)n * D + lane] = acc_p - acc_t;
    }
}

// One thread per (edge, feature): msg = t[src][f] + q[dst][f]; atomicMax into agg[dst][f].
__global__ __launch_bounds__(256) void k_edge(
    const int* __restrict__ src, const int* __restrict__ dst,
    const float* __restrict__ t, const float* __restrict__ q,
    int* __restrict__ agg)
{
    const long tid = (long)blockIdx.x * 256 + threadIdx.x;
    const int e = (int)(tid >> 6);
    const int f = (int)(tid & 63);
    if (e >= N_EDGES) return;
    const int s = src[e];
    const int d = dst[e];
    const float m = t[(long)s * D + f] + q[(long)d * D + f];
    atomicMax(&agg[(long)d * D + f], f2ord(m));
}

// Per-graph max over nodes (graph_ids sorted). Lane = feature; wave walks a node chunk,
// flushing its running max on graph-id change. Correct even if not sorted (atomicMax).
__global__ __launch_bounds__(256) void k_pool(
    const int* __restrict__ agg, const int* __restrict__ gid,
    int* __restrict__ hg)
{
    const int lane = threadIdx.x & 63;
    const int wave = threadIdx.x >> 6;
    const int NPW = 256;  // nodes per wave
    const int n0 = blockIdx.x * (NPW * 4) + wave * NPW;
    int cur = -1;
    float m = -INFINITY;
    for (int r = 0; r < NPW; ++r) {
        const int n = n0 + r;
        if (n >= N_NODES) break;
        const int g = gid[n];
        if (g != cur) {
            if (cur >= 0) atomicMax(&hg[cur * D + lane], f2ord(m));
            cur = g;
            m = -INFINITY;
        }
        const int a = agg[(long)n * D + lane];
        const float v = (a == INT_MIN) ? 0.0f : ord2f(a);
        m = fmaxf(m, v);
    }
    if (cur >= 0) atomicMax(&hg[cur * D + lane], f2ord(m));
}

// [32,64] @ [64,40] + b -> [32,40]. One block.
__global__ __launch_bounds__(256) void k_cls(
    const int* __restrict__ hg, const float* __restrict__ w,
    const float* __restrict__ b, float* __restrict__ out)
{
    __shared__ float s_h[N_GRAPHS * D];
    __shared__ float s_w[D * N_CLASSES];
    __shared__ float s_b[N_CLASSES];
    for (int i = threadIdx.x; i < N_GRAPHS * D; i += 256) s_h[i] = ord2f(hg[i]);
    for (int i = threadIdx.x; i < D * N_CLASSES; i += 256) s_w[i] = w[i];
    if (threadIdx.x < N_CLASSES) s_b[threadIdx.x] = b[threadIdx.x];
    __syncthreads();
    for (int o = threadIdx.x; o < N_GRAPHS * N_CLASSES; o += 256) {
        const int g = o / N_CLASSES;
        const int c = o % N_CLASSES;
        float acc = s_b[c];
        #pragma unroll
        for (int k = 0; k < D; ++k)
            acc = fmaf(s_h[g * D + k], s_w[k * N_CLASSES + c], acc);
        out[o] = acc;
    }
}

extern "C" void kernel_launch(void* const* d_in, const int* in_sizes, int n_in,
                              void* d_out, int out_size, void* d_ws, size_t ws_size,
                              hipStream_t stream) {
    const float* h       = (const float*)d_in[0];
    const int*   src     = (const int*)d_in[1];
    const int*   dst     = (const int*)d_in[2];
    const int*   gid     = (const int*)d_in[3];
    const float* theta_w = (const float*)d_in[4];  // [3][64][64]
    const float* theta_b = (const float*)d_in[5];  // [3][64]
    const float* phi_w   = (const float*)d_in[6];
    const float* phi_b   = (const float*)d_in[7];
    const float* cls_w   = (const float*)d_in[8];  // [64][40]
    const float* cls_b   = (const float*)d_in[9];  // [40]
    float* out = (float*)d_out;

    const size_t NF = (size_t)N_NODES * D;
    float* t   = (float*)d_ws;
    float* q   = t + NF;
    int*   agg = (int*)(q + NF);
    int*   hg  = agg + NF;
    const size_t need = (3 * NF + (size_t)N_GRAPHS * D) * sizeof(float);
    if (ws_size < need) {  // clean fail: leave zeros in out
        hipMemsetAsync(d_out, 0, (size_t)out_size * sizeof(float), stream);
        return;
    }

    const int GEMM_GRID = (N_NODES + 127) / 128;              // 128 rows/block
    const int EDGE_GRID = (int)(((long)N_EDGES * D) / 256);   // exact: 400000
    const int FILL_GRID = 2048;
    const int POOL_GRID = (N_NODES + 1023) / 1024;

    // ---- layer 0 ----
    k_fill<<<FILL_GRID, 256, 0, stream>>>(agg, (long)NF, INT_MIN);
    k_gemm_tq<false><<<GEMM_GRID, 256, 0, stream>>>(
        h, nullptr, theta_w, phi_w, theta_b, phi_b, t, q);
    k_edge<<<EDGE_GRID, 256, 0, stream>>>(src, dst, t, q, agg);

    // ---- layer 1 ----
    k_gemm_tq<true><<<GEMM_GRID, 256, 0, stream>>>(
        nullptr, agg, theta_w + D * D, phi_w + D * D, theta_b + D, phi_b + D, t, q);
    k_fill<<<FILL_GRID, 256, 0, stream>>>(agg, (long)NF, INT_MIN);
    k_edge<<<EDGE_GRID, 256, 0, stream>>>(src, dst, t, q, agg);

    // ---- layer 2 ----
    k_gemm_tq<true><<<GEMM_GRID, 256, 0, stream>>>(
        nullptr, agg, theta_w + 2 * D * D, phi_w + 2 * D * D, theta_b + 2 * D, phi_b + 2 * D, t, q);
    k_fill<<<FILL_GRID, 256, 0, stream>>>(agg, (long)NF, INT_MIN);
    k_edge<<<EDGE_GRID, 256, 0, stream>>>(src, dst, t, q, agg);

    // ---- readout ----
    k_fill<<<1, 256, 0, stream>>>(hg, (long)(N_GRAPHS * D), INT_MIN);
    k_pool<<<POOL_GRID, 256, 0, stream>>>(agg, gid, hg);
    k_cls<<<1, 256, 0, stream>>>(hg, cls_w, cls_b, out);
}

// Round 2
// 1147.214 us; speedup vs baseline: 1.3422x; 1.3422x over previous
//
#include <hip/hip_runtime.h>
#include <hip/hip_bf16.h>
#include <climits>

#define N_NODES   100000
#define N_EDGES   1600000
#define D         64
#define N_GRAPHS  32
#define N_CLASSES 40
#define SCAN_CHUNK 1024
#define N_SCAN_BLK ((N_NODES + SCAN_CHUNK - 1) / SCAN_CHUNK)  // 98

// Monotone bijection float -> int (order-preserving for signed int compare).
__device__ __forceinline__ int f2ord(float f) {
    int i = __float_as_int(f);
    return (i >= 0) ? i : (i ^ 0x7FFFFFFF);
}
__device__ __forceinline__ float ord2f(int i) {
    int j = (i >= 0) ? i : (i ^ 0x7FFFFFFF);
    return __int_as_float(j);
}

__global__ __launch_bounds__(256) void k_fill(int* __restrict__ p, long n, int v) {
    long i = (long)blockIdx.x * blockDim.x + threadIdx.x;
    long stride = (long)gridDim.x * blockDim.x;
    for (; i < n; i += stride) p[i] = v;
}

// ---------------- CSR build (by dst) ----------------

__global__ __launch_bounds__(256) void k_hist(const int* __restrict__ dst, int* __restrict__ deg) {
    int e = blockIdx.x * 256 + threadIdx.x;
    if (e < N_EDGES) atomicAdd(&deg[dst[e]], 1);
}

// Exclusive scan, stage 1: per-block (1024 elems) scan + block sums.
__global__ __launch_bounds__(256) void k_scan_block(
    const int* __restrict__ deg, int* __restrict__ rowptr, int* __restrict__ bsum)
{
    __shared__ int s[256];
    const int t = threadIdx.x;
    const int base = blockIdx.x * SCAN_CHUNK + t * 4;
    int v[4], sum = 0;
    #pragma unroll
    for (int i = 0; i < 4; ++i) {
        v[i] = (base + i < N_NODES) ? deg[base + i] : 0;
        sum += v[i];
    }
    s[t] = sum;
    __syncthreads();
    #pragma unroll
    for (int off = 1; off < 256; off <<= 1) {
        int x = (t >= off) ? s[t - off] : 0;
        __syncthreads();
        s[t] += x;
        __syncthreads();
    }
    int run = s[t] - sum;  // exclusive offset of this thread within block
    if (t == 255) bsum[blockIdx.x] = s[255];
    #pragma unroll
    for (int i = 0; i < 4; ++i) {
        if (base + i < N_NODES) rowptr[base + i] = run;
        run += v[i];
    }
}

// stage 2: exclusive scan of the 98 block sums (single block).
__global__ __launch_bounds__(128) void k_scan_top(int* __restrict__ bsum) {
    __shared__ int s[128];
    const int t = threadIdx.x;
    int v = (t < N_SCAN_BLK) ? bsum[t] : 0;
    s[t] = v;
    __syncthreads();
    #pragma unroll
    for (int off = 1; off < 128; off <<= 1) {
        int x = (t >= off) ? s[t - off] : 0;
        __syncthreads();
        s[t] += x;
        __syncthreads();
    }
    if (t < N_SCAN_BLK) bsum[t] = s[t] - v;  // exclusive
}

// stage 3: add block offsets; init cursor; set rowptr[N]=E.
__global__ __launch_bounds__(256) void k_scan_add(
    int* __restrict__ rowptr, int* __restrict__ cursor, const int* __restrict__ bsum)
{
    int i = blockIdx.x * 256 + threadIdx.x;
    if (i > N_NODES) return;
    if (i == N_NODES) {
        rowptr[N_NODES] = N_EDGES;
        return;
    }
    int r = rowptr[i] + bsum[i / SCAN_CHUNK];
    rowptr[i] = r;
    cursor[i] = r;
}

__global__ __launch_bounds__(256) void k_scatter(
    const int* __restrict__ src, const int* __restrict__ dst,
    int* __restrict__ cursor, int* __restrict__ ebuf)
{
    int e = blockIdx.x * 256 + threadIdx.x;
    if (e >= N_EDGES) return;
    int pos = atomicAdd(&cursor[dst[e]], 1);
    ebuf[pos] = src[e];
}

// ---------------- per-layer kernels ----------------

// t = bf16(h @ tw) ; q = (h @ pw + (tb+pb)) - (h @ tw).  One lane per output feature.
template <bool FROM_AGG>
__global__ __launch_bounds__(256) void k_gemm_tq(
    const float* __restrict__ h,
    const float* __restrict__ tw, const float* __restrict__ pw,
    const float* __restrict__ tb, const float* __restrict__ pb,
    __hip_bfloat16* __restrict__ t, float* __restrict__ q)
{
    __shared__ float s_tw[D * D];
    __shared__ float s_pw[D * D];
    __shared__ float s_b[D];
    for (int i = threadIdx.x; i < D * D; i += 256) {
        s_tw[i] = tw[i];
        s_pw[i] = pw[i];
    }
    if (threadIdx.x < D) s_b[threadIdx.x] = tb[threadIdx.x] + pb[threadIdx.x];
    __syncthreads();

    const int lane = threadIdx.x & 63;
    const int wave = threadIdx.x >> 6;
    const int ROWS_PER_WAVE = 32;
    const int row0 = blockIdx.x * (ROWS_PER_WAVE * 4) + wave * ROWS_PER_WAVE;

    for (int r = 0; r < ROWS_PER_WAVE; ++r) {
        const int n = row0 + r;
        if (n >= N_NODES) return;
        float hreg = h[(long)n * D + lane];  // agg path: plain float, zeros already filled
        float acc_t = 0.0f;
        float acc_p = s_b[lane];
        #pragma unroll
        for (int k = 0; k < D; ++k) {
            float hk = __shfl(hreg, k);
            acc_t = fmaf(hk, s_tw[k * D + lane], acc_t);
            acc_p = fmaf(hk, s_pw[k * D + lane], acc_p);
        }
        t[(long)n * D + lane] = __float2bfloat16(acc_t);
        q[(long)n * D + lane] = acc_p - acc_t;
    }
}

// One wave per node: agg[n] = deg>0 ? max_{s in in(n)} t[s] + q[n] : 0
__global__ __launch_bounds__(256) void k_edge_csr(
    const int* __restrict__ rowptr, const int* __restrict__ ebuf,
    const __hip_bfloat16* __restrict__ t, const float* __restrict__ q,
    float* __restrict__ agg)
{
    const int node = blockIdx.x * 4 + (threadIdx.x >> 6);
    if (node >= N_NODES) return;
    const int lane = threadIdx.x & 63;
    const int beg = rowptr[node];
    const int end = rowptr[node + 1];

    float m = -INFINITY;
    int e = beg;
    for (; e + 1 < end; e += 2) {
        const int s0 = ebuf[e];
        const int s1 = ebuf[e + 1];
        const float a = __bfloat162float(t[(long)s0 * D + lane]);
        const float b = __bfloat162float(t[(long)s1 * D + lane]);
        m = fmaxf(m, fmaxf(a, b));
    }
    if (e < end) {
        const int s0 = ebuf[e];
        m = fmaxf(m, __bfloat162float(t[(long)s0 * D + lane]));
    }
    const float out = (end > beg) ? m + q[(long)node * D + lane] : 0.0f;
    agg[(long)node * D + lane] = out;
}

// Per-graph max over nodes (graph_ids sorted). Lane = feature.
__global__ __launch_bounds__(256) void k_pool(
    const float* __restrict__ agg, const int* __restrict__ gid,
    int* __restrict__ hg)
{
    const int lane = threadIdx.x & 63;
    const int wave = threadIdx.x >> 6;
    const int NPW = 256;  // nodes per wave
    const int n0 = blockIdx.x * (NPW * 4) + wave * NPW;
    int cur = -1;
    float m = -INFINITY;
    for (int r = 0; r < NPW; ++r) {
        const int n = n0 + r;
        if (n >= N_NODES) break;
        const int g = gid[n];
        if (g != cur) {
            if (cur >= 0) atomicMax(&hg[cur * D + lane], f2ord(m));
            cur = g;
            m = -INFINITY;
        }
        m = fmaxf(m, agg[(long)n * D + lane]);
    }
    if (cur >= 0) atomicMax(&hg[cur * D + lane], f2ord(m));
}

// [32,64] @ [64,40] + b -> [32,40]. One block.
__global__ __launch_bounds__(256) void k_cls(
    const int* __restrict__ hg, const float* __restrict__ w,
    const float* __restrict__ b, float* __restrict__ out)
{
    __shared__ float s_h[N_GRAPHS * D];
    __shared__ float s_w[D * N_CLASSES];
    __shared__ float s_b[N_CLASSES];
    for (int i = threadIdx.x; i < N_GRAPHS * D; i += 256) s_h[i] = ord2f(hg[i]);
    for (int i = threadIdx.x; i < D * N_CLASSES; i += 256) s_w[i] = w[i];
    if (threadIdx.x < N_CLASSES) s_b[threadIdx.x] = b[threadIdx.x];
    __syncthreads();
    for (int o = threadIdx.x; o < N_GRAPHS * N_CLASSES; o += 256) {
        const int g = o / N_CLASSES;
        const int c = o % N_CLASSES;
        float acc = s_b[c];
        #pragma unroll
        for (int k = 0; k < D; ++k)
            acc = fmaf(s_h[g * D + k], s_w[k * N_CLASSES + c], acc);
        out[o] = acc;
    }
}

extern "C" void kernel_launch(void* const* d_in, const int* in_sizes, int n_in,
                              void* d_out, int out_size, void* d_ws, size_t ws_size,
                              hipStream_t stream) {
    const float* h       = (const float*)d_in[0];
    const int*   src     = (const int*)d_in[1];
    const int*   dst     = (const int*)d_in[2];
    const int*   gid     = (const int*)d_in[3];
    const float* theta_w = (const float*)d_in[4];  // [3][64][64]
    const float* theta_b = (const float*)d_in[5];  // [3][64]
    const float* phi_w   = (const float*)d_in[6];
    const float* phi_b   = (const float*)d_in[7];
    const float* cls_w   = (const float*)d_in[8];  // [64][40]
    const float* cls_b   = (const float*)d_in[9];  // [40]
    float* out = (float*)d_out;

    const size_t NF = (size_t)N_NODES * D;
    // layout (bytes):
    char* p = (char*)d_ws;
    __hip_bfloat16* t = (__hip_bfloat16*)p;          p += NF * 2;                 // 12.8 MB
    float* q          = (float*)p;                   p += NF * 4;                 // 25.6 MB
    float* agg        = (float*)p;                   p += NF * 4;                 // 25.6 MB
    int* rowptr       = (int*)p;                     p += (N_NODES + 1) * 4;
    int* cursor       = (int*)p;                     p += N_NODES * 4;
    int* deg          = (int*)p;                     p += N_NODES * 4;
    int* ebuf         = (int*)p;                     p += (size_t)N_EDGES * 4;    // 6.4 MB
    int* bsum         = (int*)p;                     p += 128 * 4;
    int* hg           = (int*)p;                     p += N_GRAPHS * D * 4;
    const size_t need = (size_t)(p - (char*)d_ws);
    if (ws_size < need) {
        hipMemsetAsync(d_out, 0, (size_t)out_size * sizeof(float), stream);
        return;
    }

    const int GEMM_GRID = (N_NODES + 127) / 128;
    const int EDGE_GRID = (N_NODES + 3) / 4;
    const int E_GRID    = (N_EDGES + 255) / 256;

    // ---- build CSR by dst (once; shared by all 3 layers) ----
    k_fill<<<(N_NODES + 255) / 256, 256, 0, stream>>>(deg, N_NODES, 0);
    k_hist<<<E_GRID, 256, 0, stream>>>(dst, deg);
    k_scan_block<<<N_SCAN_BLK, 256, 0, stream>>>(deg, rowptr, bsum);
    k_scan_top<<<1, 128, 0, stream>>>(bsum);
    k_scan_add<<<(N_NODES + 256) / 256, 256, 0, stream>>>(rowptr, cursor, bsum);
    k_scatter<<<E_GRID, 256, 0, stream>>>(src, dst, cursor, ebuf);

    // ---- 3 EdgeConv layers ----
    k_gemm_tq<false><<<GEMM_GRID, 256, 0, stream>>>(h, theta_w, phi_w, theta_b, phi_b, t, q);
    k_edge_csr<<<EDGE_GRID, 256, 0, stream>>>(rowptr, ebuf, t, q, agg);

    k_gemm_tq<true><<<GEMM_GRID, 256, 0, stream>>>(
        agg, theta_w + D * D, phi_w + D * D, theta_b + D, phi_b + D, t, q);
    k_edge_csr<<<EDGE_GRID, 256, 0, stream>>>(rowptr, ebuf, t, q, agg);

    k_gemm_tq<true><<<GEMM_GRID, 256, 0, stream>>>(
        agg, theta_w + 2 * D * D, phi_w + 2 * D * D, theta_b + 2 * D, phi_b + 2 * D, t, q);
    k_edge_csr<<<EDGE_GRID, 256, 0, stream>>>(rowptr, ebuf, t, q, agg);

    // ---- readout ----
    k_fill<<<8, 256, 0, stream>>>(hg, (long)(N_GRAPHS * D), INT_MIN);
    k_pool<<<(N_NODES + 1023) / 1024, 256, 0, stream>>>(agg, gid, hg);
    k_cls<<<1, 256, 0, stream>>>(hg, cls_w, cls_b, out);
}

// Round 3
// 635.753 us; speedup vs baseline: 2.4221x; 1.8045x over previous
//
#include <hip/hip_runtime.h>
#include <hip/hip_bf16.h>
#include <climits>

#define N_NODES   100000
#define N_EDGES   1600000
#define D         64
#define N_GRAPHS  32
#define N_CLASSES 40
#define SCAN_CHUNK 1024
#define N_SCAN_BLK ((N_NODES + SCAN_CHUNK - 1) / SCAN_CHUNK)  // 98
#define N_TILES   (N_NODES / 16)   // 6250 row-tiles of 16
#define TPW       2                // row-tiles per wave
#define GEMM_WAVES ((N_TILES + TPW - 1) / TPW)        // 3125
#define GEMM_BLOCKS ((GEMM_WAVES + 3) / 4)            // 782

typedef __bf16 bf16_t;
typedef bf16_t bf16x8 __attribute__((ext_vector_type(8)));
typedef float  f32x4  __attribute__((ext_vector_type(4)));

// Monotone bijection float -> int (order-preserving for signed int compare).
__device__ __forceinline__ int f2ord(float f) {
    int i = __float_as_int(f);
    return (i >= 0) ? i : (i ^ 0x7FFFFFFF);
}
__device__ __forceinline__ float ord2f(int i) {
    int j = (i >= 0) ? i : (i ^ 0x7FFFFFFF);
    return __int_as_float(j);
}

__global__ __launch_bounds__(256) void k_fill(int* __restrict__ p, long n, int v) {
    long i = (long)blockIdx.x * blockDim.x + threadIdx.x;
    long stride = (long)gridDim.x * blockDim.x;
    for (; i < n; i += stride) p[i] = v;
}

// ---------------- weight prep: wcat[l][n][k] = (n<64 ? tw : pw)[l][k][n%64], bf16 ----------------
__global__ __launch_bounds__(256) void k_prep(
    const float* __restrict__ tw, const float* __restrict__ pw,
    const float* __restrict__ tb, const float* __restrict__ pb,
    bf16_t* __restrict__ wcat, float* __restrict__ bcat)
{
    const int i = blockIdx.x * 256 + threadIdx.x;
    if (i < 3 * 128 * 64) {
        const int l = i >> 13;
        const int rem = i & 8191;
        const int n = rem >> 6;
        const int k = rem & 63;
        const float v = (n < D) ? tw[l * 4096 + k * D + n] : pw[l * 4096 + k * D + (n - D)];
        wcat[i] = (bf16_t)v;
    }
    if (i < 3 * D) bcat[i] = tb[i] + pb[i];
}

// ---------------- CSR build (by dst) ----------------

__global__ __launch_bounds__(256) void k_hist(const int* __restrict__ dst, int* __restrict__ deg) {
    int e = blockIdx.x * 256 + threadIdx.x;
    if (e < N_EDGES) atomicAdd(&deg[dst[e]], 1);
}

__global__ __launch_bounds__(256) void k_scan_block(
    const int* __restrict__ deg, int* __restrict__ rowptr, int* __restrict__ bsum)
{
    __shared__ int s[256];
    const int t = threadIdx.x;
    const int base = blockIdx.x * SCAN_CHUNK + t * 4;
    int v[4], sum = 0;
    #pragma unroll
    for (int i = 0; i < 4; ++i) {
        v[i] = (base + i < N_NODES) ? deg[base + i] : 0;
        sum += v[i];
    }
    s[t] = sum;
    __syncthreads();
    #pragma unroll
    for (int off = 1; off < 256; off <<= 1) {
        int x = (t >= off) ? s[t - off] : 0;
        __syncthreads();
        s[t] += x;
        __syncthreads();
    }
    int run = s[t] - sum;
    if (t == 255) bsum[blockIdx.x] = s[255];
    #pragma unroll
    for (int i = 0; i < 4; ++i) {
        if (base + i < N_NODES) rowptr[base + i] = run;
        run += v[i];
    }
}

__global__ __launch_bounds__(128) void k_scan_top(int* __restrict__ bsum) {
    __shared__ int s[128];
    const int t = threadIdx.x;
    int v = (t < N_SCAN_BLK) ? bsum[t] : 0;
    s[t] = v;
    __syncthreads();
    #pragma unroll
    for (int off = 1; off < 128; off <<= 1) {
        int x = (t >= off) ? s[t - off] : 0;
        __syncthreads();
        s[t] += x;
        __syncthreads();
    }
    if (t < N_SCAN_BLK) bsum[t] = s[t] - v;
}

__global__ __launch_bounds__(256) void k_scan_add(
    int* __restrict__ rowptr, int* __restrict__ cursor, const int* __restrict__ bsum)
{
    int i = blockIdx.x * 256 + threadIdx.x;
    if (i > N_NODES) return;
    if (i == N_NODES) {
        rowptr[N_NODES] = N_EDGES;
        return;
    }
    int r = rowptr[i] + bsum[i / SCAN_CHUNK];
    rowptr[i] = r;
    cursor[i] = r;
}

__global__ __launch_bounds__(256) void k_scatter(
    const int* __restrict__ src, const int* __restrict__ dst,
    int* __restrict__ cursor, int* __restrict__ ebuf)
{
    int e = blockIdx.x * 256 + threadIdx.x;
    if (e >= N_EDGES) return;
    int pos = atomicAdd(&cursor[dst[e]], 1);
    ebuf[pos] = src[e];
}

// ---------------- fused node GEMM via MFMA: t = bf16(A@tw), q = bf16(A@pw + b - A@tw) ----------------
// A = f32 h (layer 0) or bf16 agg (layers 1-2). Weights pre-transposed: wcat[n][k], n in [0,128).
// m97-verified fragment pattern: A-frag & B-frag = 8 contiguous k at row (lane&15), k-off 8*(lane>>4);
// D: row=(lane>>4)*4+reg, col=lane&15.
template <bool FROM_F32>
__global__ __launch_bounds__(256) void k_gemm_mfma(
    const float* __restrict__ hf, const bf16_t* __restrict__ hb,
    const bf16_t* __restrict__ wcat,  // [128][64] this layer
    const float* __restrict__ bcat,   // [64] this layer
    bf16_t* __restrict__ t, bf16_t* __restrict__ q)
{
    const int lane = threadIdx.x & 63;
    const int wid  = blockIdx.x * 4 + (threadIdx.x >> 6);
    const int r16  = lane & 15;
    const int kg   = lane >> 4;   // 0..3
    const int koff = kg * 8;

    // B fragments: col-tiles c=0..7 (cols c*16..c*16+15), k-steps s=0..1. Kept in regs.
    bf16x8 bfrag[8][2];
    #pragma unroll
    for (int c = 0; c < 8; ++c)
        #pragma unroll
        for (int s = 0; s < 2; ++s)
            bfrag[c][s] = *(const bf16x8*)&wcat[(c * 16 + r16) * D + s * 32 + koff];

    float bias[4];
    #pragma unroll
    for (int c = 0; c < 4; ++c) bias[c] = bcat[c * 16 + r16];

    #pragma unroll
    for (int tt = 0; tt < TPW; ++tt) {
        const int tile = wid * TPW + tt;
        if (tile >= N_TILES) return;
        const long rowbase = (long)tile * 16;
        const long arow = rowbase + r16;

        bf16x8 afrag[2];
        if (FROM_F32) {
            #pragma unroll
            for (int s = 0; s < 2; ++s) {
                const f32x4 v0 = *(const f32x4*)&hf[arow * D + s * 32 + koff];
                const f32x4 v1 = *(const f32x4*)&hf[arow * D + s * 32 + koff + 4];
                bf16x8 a;
                a[0] = (bf16_t)v0[0]; a[1] = (bf16_t)v0[1];
                a[2] = (bf16_t)v0[2]; a[3] = (bf16_t)v0[3];
                a[4] = (bf16_t)v1[0]; a[5] = (bf16_t)v1[1];
                a[6] = (bf16_t)v1[2]; a[7] = (bf16_t)v1[3];
                afrag[s] = a;
            }
        } else {
            afrag[0] = *(const bf16x8*)&hb[arow * D + koff];
            afrag[1] = *(const bf16x8*)&hb[arow * D + 32 + koff];
        }

        const f32x4 zero = {0.0f, 0.0f, 0.0f, 0.0f};
        f32x4 acc[8];
        #pragma unroll
        for (int c = 0; c < 8; ++c) {
            acc[c] = __builtin_amdgcn_mfma_f32_16x16x32_bf16(afrag[0], bfrag[c][0], zero, 0, 0, 0);
            acc[c] = __builtin_amdgcn_mfma_f32_16x16x32_bf16(afrag[1], bfrag[c][1], acc[c], 0, 0, 0);
        }

        // epilogue: cols 0-63 are t, 64-127 are p; q = p - t + bias (same lane holds both)
        #pragma unroll
        for (int c = 0; c < 4; ++c) {
            #pragma unroll
            for (int j = 0; j < 4; ++j) {
                const long R = rowbase + kg * 4 + j;
                const int f = c * 16 + r16;
                t[R * D + f] = (bf16_t)acc[c][j];
                q[R * D + f] = (bf16_t)(acc[c + 4][j] - acc[c][j] + bias[c]);
            }
        }
    }
}

// ---------------- gather-max per node ----------------
// One wave per node: agg[n] = deg>0 ? bf16(max_{s in in(n)} t[s] + q[n]) : 0
__global__ __launch_bounds__(256) void k_edge_csr(
    const int* __restrict__ rowptr, const int* __restrict__ ebuf,
    const bf16_t* __restrict__ t, const bf16_t* __restrict__ q,
    bf16_t* __restrict__ agg)
{
    const int node = blockIdx.x * 4 + (threadIdx.x >> 6);
    if (node >= N_NODES) return;
    const int lane = threadIdx.x & 63;
    const int beg = rowptr[node];
    const int end = rowptr[node + 1];

    float m = -INFINITY;
    int e = beg;
    for (; e + 3 < end; e += 4) {
        const int s0 = ebuf[e];
        const int s1 = ebuf[e + 1];
        const int s2 = ebuf[e + 2];
        const int s3 = ebuf[e + 3];
        const float a = (float)t[(long)s0 * D + lane];
        const float b = (float)t[(long)s1 * D + lane];
        const float c = (float)t[(long)s2 * D + lane];
        const float d = (float)t[(long)s3 * D + lane];
        m = fmaxf(m, fmaxf(fmaxf(a, b), fmaxf(c, d)));
    }
    for (; e < end; ++e) {
        const int s0 = ebuf[e];
        m = fmaxf(m, (float)t[(long)s0 * D + lane]);
    }
    const float out = (end > beg) ? m + (float)q[(long)node * D + lane] : 0.0f;
    agg[(long)node * D + lane] = (bf16_t)out;
}

// ---------------- readout ----------------
__global__ __launch_bounds__(256) void k_pool(
    const bf16_t* __restrict__ agg, const int* __restrict__ gid,
    int* __restrict__ hg)
{
    const int lane = threadIdx.x & 63;
    const int wave = threadIdx.x >> 6;
    const int NPW = 256;
    const int n0 = blockIdx.x * (NPW * 4) + wave * NPW;
    int cur = -1;
    float m = -INFINITY;
    for (int r = 0; r < NPW; ++r) {
        const int n = n0 + r;
        if (n >= N_NODES) break;
        const int g = gid[n];
        if (g != cur) {
            if (cur >= 0) atomicMax(&hg[cur * D + lane], f2ord(m));
            cur = g;
            m = -INFINITY;
        }
        m = fmaxf(m, (float)agg[(long)n * D + lane]);
    }
    if (cur >= 0) atomicMax(&hg[cur * D + lane], f2ord(m));
}

__global__ __launch_bounds__(256) void k_cls(
    const int* __restrict__ hg, const float* __restrict__ w,
    const float* __restrict__ b, float* __restrict__ out)
{
    __shared__ float s_h[N_GRAPHS * D];
    __shared__ float s_w[D * N_CLASSES];
    __shared__ float s_b[N_CLASSES];
    for (int i = threadIdx.x; i < N_GRAPHS * D; i += 256) s_h[i] = ord2f(hg[i]);
    for (int i = threadIdx.x; i < D * N_CLASSES; i += 256) s_w[i] = w[i];
    if (threadIdx.x < N_CLASSES) s_b[threadIdx.x] = b[threadIdx.x];
    __syncthreads();
    for (int o = threadIdx.x; o < N_GRAPHS * N_CLASSES; o += 256) {
        const int g = o / N_CLASSES;
        const int c = o % N_CLASSES;
        float acc = s_b[c];
        #pragma unroll
        for (int k = 0; k < D; ++k)
            acc = fmaf(s_h[g * D + k], s_w[k * N_CLASSES + c], acc);
        out[o] = acc;
    }
}

extern "C" void kernel_launch(void* const* d_in, const int* in_sizes, int n_in,
                              void* d_out, int out_size, void* d_ws, size_t ws_size,
                              hipStream_t stream) {
    const float* h       = (const float*)d_in[0];
    const int*   src     = (const int*)d_in[1];
    const int*   dst     = (const int*)d_in[2];
    const int*   gid     = (const int*)d_in[3];
    const float* theta_w = (const float*)d_in[4];
    const float* theta_b = (const float*)d_in[5];
    const float* phi_w   = (const float*)d_in[6];
    const float* phi_b   = (const float*)d_in[7];
    const float* cls_w   = (const float*)d_in[8];
    const float* cls_b   = (const float*)d_in[9];
    float* out = (float*)d_out;

    const size_t NF = (size_t)N_NODES * D;
    char* p = (char*)d_ws;
    bf16_t* t    = (bf16_t*)p;  p += NF * 2;                 // 12.8 MB
    bf16_t* q    = (bf16_t*)p;  p += NF * 2;                 // 12.8 MB
    bf16_t* agg  = (bf16_t*)p;  p += NF * 2;                 // 12.8 MB
    bf16_t* wcat = (bf16_t*)p;  p += 3 * 128 * D * 2;        // 48 KB (16B-aligned offset)
    float*  bcat = (float*)p;   p += 3 * D * 4;
    int* rowptr  = (int*)p;     p += (N_NODES + 1) * 4;
    int* cursor  = (int*)p;     p += N_NODES * 4;
    int* deg     = (int*)p;     p += N_NODES * 4;
    int* ebuf    = (int*)p;     p += (size_t)N_EDGES * 4;    // 6.4 MB
    int* bsum    = (int*)p;     p += 128 * 4;
    int* hg      = (int*)p;     p += N_GRAPHS * D * 4;
    const size_t need = (size_t)(p - (char*)d_ws);
    if (ws_size < need) {
        hipMemsetAsync(d_out, 0, (size_t)out_size * sizeof(float), stream);
        return;
    }

    const int EDGE_GRID = (N_NODES + 3) / 4;
    const int E_GRID    = (N_EDGES + 255) / 256;

    // ---- prep: transposed bf16 weights + fused biases ----
    k_prep<<<96, 256, 0, stream>>>(theta_w, phi_w, theta_b, phi_b, wcat, bcat);

    // ---- build CSR by dst (once; shared by all 3 layers) ----
    k_fill<<<(N_NODES + 255) / 256, 256, 0, stream>>>(deg, N_NODES, 0);
    k_hist<<<E_GRID, 256, 0, stream>>>(dst, deg);
    k_scan_block<<<N_SCAN_BLK, 256, 0, stream>>>(deg, rowptr, bsum);
    k_scan_top<<<1, 128, 0, stream>>>(bsum);
    k_scan_add<<<(N_NODES + 256) / 256, 256, 0, stream>>>(rowptr, cursor, bsum);
    k_scatter<<<E_GRID, 256, 0, stream>>>(src, dst, cursor, ebuf);

    // ---- 3 EdgeConv layers ----
    k_gemm_mfma<true><<<GEMM_BLOCKS, 256, 0, stream>>>(h, nullptr, wcat, bcat, t, q);
    k_edge_csr<<<EDGE_GRID, 256, 0, stream>>>(rowptr, ebuf, t, q, agg);

    k_gemm_mfma<false><<<GEMM_BLOCKS, 256, 0, stream>>>(
        nullptr, agg, wcat + 128 * D, bcat + D, t, q);
    k_edge_csr<<<EDGE_GRID, 256, 0, stream>>>(rowptr, ebuf, t, q, agg);

    k_gemm_mfma<false><<<GEMM_BLOCKS, 256, 0, stream>>>(
        nullptr, agg, wcat + 2 * 128 * D, bcat + 2 * D, t, q);
    k_edge_csr<<<EDGE_GRID, 256, 0, stream>>>(rowptr, ebuf, t, q, agg);

    // ---- readout ----
    k_fill<<<8, 256, 0, stream>>>(hg, (long)(N_GRAPHS * D), INT_MIN);
    k_pool<<<(N_NODES + 1023) / 1024, 256, 0, stream>>>(agg, gid, hg);
    k_cls<<<1, 256, 0, stream>>>(hg, cls_w, cls_b, out);
}

// Round 4
// 510.110 us; speedup vs baseline: 3.0186x; 1.2463x over previous
//
#include <hip/hip_runtime.h>
#include <hip/hip_bf16.h>
#include <climits>

#define N_NODES   100000
#define N_EDGES   1600000
#define D         64
#define N_GRAPHS  32
#define N_CLASSES 40
#define SCAN_CHUNK 1024
#define N_SCAN_BLK ((N_NODES + SCAN_CHUNK - 1) / SCAN_CHUNK)  // 98
#define N_TILES   (N_NODES / 16)   // 6250 row-tiles of 16
#define TPW       2                // row-tiles per wave
#define GEMM_WAVES ((N_TILES + TPW - 1) / TPW)        // 3125
#define GEMM_BLOCKS ((GEMM_WAVES + 3) / 4)            // 782
#define POOL_NPW  32               // nodes per wave in k_pool

typedef __bf16 bf16_t;
typedef bf16_t bf16x8 __attribute__((ext_vector_type(8)));
typedef float  f32x4  __attribute__((ext_vector_type(4)));

// Monotone bijection float -> int (order-preserving for signed int compare).
__device__ __forceinline__ int f2ord(float f) {
    int i = __float_as_int(f);
    return (i >= 0) ? i : (i ^ 0x7FFFFFFF);
}
__device__ __forceinline__ float ord2f(int i) {
    int j = (i >= 0) ? i : (i ^ 0x7FFFFFFF);
    return __int_as_float(j);
}

__global__ __launch_bounds__(256) void k_fill(int* __restrict__ p, long n, int v) {
    long i = (long)blockIdx.x * blockDim.x + threadIdx.x;
    long stride = (long)gridDim.x * blockDim.x;
    for (; i < n; i += stride) p[i] = v;
}

// ---------------- weight prep: wcat[l][n][k] = (n<64 ? tw : pw)[l][k][n%64], bf16 ----------------
__global__ __launch_bounds__(256) void k_prep(
    const float* __restrict__ tw, const float* __restrict__ pw,
    const float* __restrict__ tb, const float* __restrict__ pb,
    bf16_t* __restrict__ wcat, float* __restrict__ bcat)
{
    const int i = blockIdx.x * 256 + threadIdx.x;
    if (i < 3 * 128 * 64) {
        const int l = i >> 13;
        const int rem = i & 8191;
        const int n = rem >> 6;
        const int k = rem & 63;
        const float v = (n < D) ? tw[l * 4096 + k * D + n] : pw[l * 4096 + k * D + (n - D)];
        wcat[i] = (bf16_t)v;
    }
    if (i < 3 * D) bcat[i] = tb[i] + pb[i];
}

// ---------------- CSR build (by dst) ----------------

__global__ __launch_bounds__(256) void k_hist(const int* __restrict__ dst, int* __restrict__ deg) {
    int e = blockIdx.x * 256 + threadIdx.x;
    if (e < N_EDGES) atomicAdd(&deg[dst[e]], 1);
}

__global__ __launch_bounds__(256) void k_scan_block(
    const int* __restrict__ deg, int* __restrict__ rowptr, int* __restrict__ bsum)
{
    __shared__ int s[256];
    const int t = threadIdx.x;
    const int base = blockIdx.x * SCAN_CHUNK + t * 4;
    int v[4], sum = 0;
    #pragma unroll
    for (int i = 0; i < 4; ++i) {
        v[i] = (base + i < N_NODES) ? deg[base + i] : 0;
        sum += v[i];
    }
    s[t] = sum;
    __syncthreads();
    #pragma unroll
    for (int off = 1; off < 256; off <<= 1) {
        int x = (t >= off) ? s[t - off] : 0;
        __syncthreads();
        s[t] += x;
        __syncthreads();
    }
    int run = s[t] - sum;
    if (t == 255) bsum[blockIdx.x] = s[255];
    #pragma unroll
    for (int i = 0; i < 4; ++i) {
        if (base + i < N_NODES) rowptr[base + i] = run;
        run += v[i];
    }
}

__global__ __launch_bounds__(128) void k_scan_top(int* __restrict__ bsum) {
    __shared__ int s[128];
    const int t = threadIdx.x;
    int v = (t < N_SCAN_BLK) ? bsum[t] : 0;
    s[t] = v;
    __syncthreads();
    #pragma unroll
    for (int off = 1; off < 128; off <<= 1) {
        int x = (t >= off) ? s[t - off] : 0;
        __syncthreads();
        s[t] += x;
        __syncthreads();
    }
    if (t < N_SCAN_BLK) bsum[t] = s[t] - v;
}

__global__ __launch_bounds__(256) void k_scan_add(
    int* __restrict__ rowptr, int* __restrict__ cursor, const int* __restrict__ bsum)
{
    int i = blockIdx.x * 256 + threadIdx.x;
    if (i > N_NODES) return;
    if (i == N_NODES) {
        rowptr[N_NODES] = N_EDGES;
        return;
    }
    int r = rowptr[i] + bsum[i / SCAN_CHUNK];
    rowptr[i] = r;
    cursor[i] = r;
}

__global__ __launch_bounds__(256) void k_scatter(
    const int* __restrict__ src, const int* __restrict__ dst,
    int* __restrict__ cursor, int* __restrict__ ebuf)
{
    int e = blockIdx.x * 256 + threadIdx.x;
    if (e >= N_EDGES) return;
    int pos = atomicAdd(&cursor[dst[e]], 1);
    ebuf[pos] = src[e];
}

// ---------------- fused node GEMM via MFMA: t = bf16(A@tw), q = bf16(A@pw + b - A@tw) ----------------
template <bool FROM_F32>
__global__ __launch_bounds__(256) void k_gemm_mfma(
    const float* __restrict__ hf, const bf16_t* __restrict__ hb,
    const bf16_t* __restrict__ wcat,  // [128][64] this layer
    const float* __restrict__ bcat,   // [64] this layer
    bf16_t* __restrict__ t, bf16_t* __restrict__ q)
{
    const int lane = threadIdx.x & 63;
    const int wid  = blockIdx.x * 4 + (threadIdx.x >> 6);
    const int r16  = lane & 15;
    const int kg   = lane >> 4;   // 0..3
    const int koff = kg * 8;

    bf16x8 bfrag[8][2];
    #pragma unroll
    for (int c = 0; c < 8; ++c)
        #pragma unroll
        for (int s = 0; s < 2; ++s)
            bfrag[c][s] = *(const bf16x8*)&wcat[(c * 16 + r16) * D + s * 32 + koff];

    float bias[4];
    #pragma unroll
    for (int c = 0; c < 4; ++c) bias[c] = bcat[c * 16 + r16];

    #pragma unroll
    for (int tt = 0; tt < TPW; ++tt) {
        const int tile = wid * TPW + tt;
        if (tile >= N_TILES) return;
        const long rowbase = (long)tile * 16;
        const long arow = rowbase + r16;

        bf16x8 afrag[2];
        if (FROM_F32) {
            #pragma unroll
            for (int s = 0; s < 2; ++s) {
                const f32x4 v0 = *(const f32x4*)&hf[arow * D + s * 32 + koff];
                const f32x4 v1 = *(const f32x4*)&hf[arow * D + s * 32 + koff + 4];
                bf16x8 a;
                a[0] = (bf16_t)v0[0]; a[1] = (bf16_t)v0[1];
                a[2] = (bf16_t)v0[2]; a[3] = (bf16_t)v0[3];
                a[4] = (bf16_t)v1[0]; a[5] = (bf16_t)v1[1];
                a[6] = (bf16_t)v1[2]; a[7] = (bf16_t)v1[3];
                afrag[s] = a;
            }
        } else {
            afrag[0] = *(const bf16x8*)&hb[arow * D + koff];
            afrag[1] = *(const bf16x8*)&hb[arow * D + 32 + koff];
        }

        const f32x4 zero = {0.0f, 0.0f, 0.0f, 0.0f};
        f32x4 acc[8];
        #pragma unroll
        for (int c = 0; c < 8; ++c) {
            acc[c] = __builtin_amdgcn_mfma_f32_16x16x32_bf16(afrag[0], bfrag[c][0], zero, 0, 0, 0);
            acc[c] = __builtin_amdgcn_mfma_f32_16x16x32_bf16(afrag[1], bfrag[c][1], acc[c], 0, 0, 0);
        }

        #pragma unroll
        for (int c = 0; c < 4; ++c) {
            #pragma unroll
            for (int j = 0; j < 4; ++j) {
                const long R = rowbase + kg * 4 + j;
                const int f = c * 16 + r16;
                t[R * D + f] = (bf16_t)acc[c][j];
                q[R * D + f] = (bf16_t)(acc[c + 4][j] - acc[c][j] + bias[c]);
            }
        }
    }
}

// ---------------- gather-max per node ----------------
__global__ __launch_bounds__(256) void k_edge_csr(
    const int* __restrict__ rowptr, const int* __restrict__ ebuf,
    const bf16_t* __restrict__ t, const bf16_t* __restrict__ q,
    bf16_t* __restrict__ agg)
{
    const int node = blockIdx.x * 4 + (threadIdx.x >> 6);
    if (node >= N_NODES) return;
    const int lane = threadIdx.x & 63;
    const int beg = rowptr[node];
    const int end = rowptr[node + 1];

    float m = -INFINITY;
    int e = beg;
    for (; e + 3 < end; e += 4) {
        const int s0 = ebuf[e];
        const int s1 = ebuf[e + 1];
        const int s2 = ebuf[e + 2];
        const int s3 = ebuf[e + 3];
        const float a = (float)t[(long)s0 * D + lane];
        const float b = (float)t[(long)s1 * D + lane];
        const float c = (float)t[(long)s2 * D + lane];
        const float d = (float)t[(long)s3 * D + lane];
        m = fmaxf(m, fmaxf(fmaxf(a, b), fmaxf(c, d)));
    }
    for (; e < end; ++e) {
        const int s0 = ebuf[e];
        m = fmaxf(m, (float)t[(long)s0 * D + lane]);
    }
    const float out = (end > beg) ? m + (float)q[(long)node * D + lane] : 0.0f;
    agg[(long)node * D + lane] = (bf16_t)out;
}

// ---------------- readout ----------------
// 32 nodes per wave; graph_ids sorted so ~1 flush per wave.
__global__ __launch_bounds__(256) void k_pool(
    const bf16_t* __restrict__ agg, const int* __restrict__ gid,
    int* __restrict__ hg)
{
    const int lane = threadIdx.x & 63;
    const int wave = threadIdx.x >> 6;
    const int n0 = (blockIdx.x * 4 + wave) * POOL_NPW;
    if (n0 >= N_NODES) return;
    const int nend = (n0 + POOL_NPW < N_NODES) ? n0 + POOL_NPW : N_NODES;
    int cur = gid[n0];
    float m = -INFINITY;
    for (int n = n0; n < nend; ++n) {
        const int g = gid[n];
        if (g != cur) {
            atomicMax(&hg[cur * D + lane], f2ord(m));
            cur = g;
            m = -INFINITY;
        }
        m = fmaxf(m, (float)agg[(long)n * D + lane]);
    }
    atomicMax(&hg[cur * D + lane], f2ord(m));
}

__global__ __launch_bounds__(256) void k_cls(
    const int* __restrict__ hg, const float* __restrict__ w,
    const float* __restrict__ b, float* __restrict__ out)
{
    __shared__ float s_h[N_GRAPHS * D];
    __shared__ float s_w[D * N_CLASSES];
    __shared__ float s_b[N_CLASSES];
    for (int i = threadIdx.x; i < N_GRAPHS * D; i += 256) s_h[i] = ord2f(hg[i]);
    for (int i = threadIdx.x; i < D * N_CLASSES; i += 256) s_w[i] = w[i];
    if (threadIdx.x < N_CLASSES) s_b[threadIdx.x] = b[threadIdx.x];
    __syncthreads();
    for (int o = threadIdx.x; o < N_GRAPHS * N_CLASSES; o += 256) {
        const int g = o / N_CLASSES;
        const int c = o % N_CLASSES;
        float acc = s_b[c];
        #pragma unroll
        for (int k = 0; k < D; ++k)
            acc = fmaf(s_h[g * D + k], s_w[k * N_CLASSES + c], acc);
        out[o] = acc;
    }
}

extern "C" void kernel_launch(void* const* d_in, const int* in_sizes, int n_in,
                              void* d_out, int out_size, void* d_ws, size_t ws_size,
                              hipStream_t stream) {
    const float* h       = (const float*)d_in[0];
    const int*   src     = (const int*)d_in[1];
    const int*   dst     = (const int*)d_in[2];
    const int*   gid     = (const int*)d_in[3];
    const float* theta_w = (const float*)d_in[4];
    const float* theta_b = (const float*)d_in[5];
    const float* phi_w   = (const float*)d_in[6];
    const float* phi_b   = (const float*)d_in[7];
    const float* cls_w   = (const float*)d_in[8];
    const float* cls_b   = (const float*)d_in[9];
    float* out = (float*)d_out;

    const size_t NF = (size_t)N_NODES * D;
    char* p = (char*)d_ws;
    bf16_t* t    = (bf16_t*)p;  p += NF * 2;                 // 12.8 MB
    bf16_t* q    = (bf16_t*)p;  p += NF * 2;                 // 12.8 MB
    bf16_t* agg  = (bf16_t*)p;  p += NF * 2;                 // 12.8 MB
    bf16_t* wcat = (bf16_t*)p;  p += 3 * 128 * D * 2;        // 48 KB
    float*  bcat = (float*)p;   p += 3 * D * 4;
    int* rowptr  = (int*)p;     p += (N_NODES + 1) * 4;
    int* cursor  = (int*)p;     p += N_NODES * 4;
    int* deg     = (int*)p;     p += N_NODES * 4;
    int* ebuf    = (int*)p;     p += (size_t)N_EDGES * 4;    // 6.4 MB
    int* bsum    = (int*)p;     p += 128 * 4;
    int* hg      = (int*)p;     p += N_GRAPHS * D * 4;
    const size_t need = (size_t)(p - (char*)d_ws);
    if (ws_size < need) {
        hipMemsetAsync(d_out, 0, (size_t)out_size * sizeof(float), stream);
        return;
    }

    const int EDGE_GRID = (N_NODES + 3) / 4;
    const int E_GRID    = (N_EDGES + 255) / 256;
    const int POOL_GRID = (N_NODES + POOL_NPW * 4 - 1) / (POOL_NPW * 4);  // 782

    // ---- prep: transposed bf16 weights + fused biases ----
    k_prep<<<96, 256, 0, stream>>>(theta_w, phi_w, theta_b, phi_b, wcat, bcat);

    // ---- build CSR by dst (once; shared by all 3 layers) ----
    k_fill<<<(N_NODES + 255) / 256, 256, 0, stream>>>(deg, N_NODES, 0);
    k_hist<<<E_GRID, 256, 0, stream>>>(dst, deg);
    k_scan_block<<<N_SCAN_BLK, 256, 0, stream>>>(deg, rowptr, bsum);
    k_scan_top<<<1, 128, 0, stream>>>(bsum);
    k_scan_add<<<(N_NODES + 256) / 256, 256, 0, stream>>>(rowptr, cursor, bsum);
    k_scatter<<<E_GRID, 256, 0, stream>>>(src, dst, cursor, ebuf);

    // ---- 3 EdgeConv layers ----
    k_gemm_mfma<true><<<GEMM_BLOCKS, 256, 0, stream>>>(h, nullptr, wcat, bcat, t, q);
    k_edge_csr<<<EDGE_GRID, 256, 0, stream>>>(rowptr, ebuf, t, q, agg);

    k_gemm_mfma<false><<<GEMM_BLOCKS, 256, 0, stream>>>(
        nullptr, agg, wcat + 128 * D, bcat + D, t, q);
    k_edge_csr<<<EDGE_GRID, 256, 0, stream>>>(rowptr, ebuf, t, q, agg);

    k_gemm_mfma<false><<<GEMM_BLOCKS, 256, 0, stream>>>(
        nullptr, agg, wcat + 2 * 128 * D, bcat + 2 * D, t, q);
    k_edge_csr<<<EDGE_GRID, 256, 0, stream>>>(rowptr, ebuf, t, q, agg);

    // ---- readout ----
    k_fill<<<8, 256, 0, stream>>>(hg, (long)(N_GRAPHS * D), INT_MIN);
    k_pool<<<POOL_GRID, 256, 0, stream>>>(agg, gid, hg);
    k_cls<<<1, 256, 0, stream>>>(hg, cls_w, cls_b, out);
}